// Round 1
// 414.107 us; speedup vs baseline: 1.0829x; 1.0829x over previous
//
#include <hip/hip_runtime.h>
#include <cstdint>
#include <cstddef>

// Problem constants
#define TB 4
#define TT 2048
#define TC 1024
#define NH 16
#define HD 64
#define MROWS (TB * TT)   // 8192

typedef __bf16 bf16;
typedef unsigned short u16;
typedef __bf16 bf16x8 __attribute__((ext_vector_type(8)));
typedef float floatx4 __attribute__((ext_vector_type(4)));
typedef unsigned short ushort8 __attribute__((ext_vector_type(8)));
typedef unsigned short ushort4v __attribute__((ext_vector_type(4)));

#define LOG2E 1.4426950408889634f

static __device__ __forceinline__ u16 f2bfbits(float f) {
    bf16 b = (bf16)f;
    return __builtin_bit_cast(u16, b);
}

#if __has_builtin(__builtin_amdgcn_exp2f)
#define EXP2F(x) __builtin_amdgcn_exp2f(x)
#else
#define EXP2F(x) exp2f(x)
#endif

// async global->LDS 16B (dest = wave-uniform base + lane*16)
static __device__ __forceinline__ void gld_lds16(const u16* g, const u16* lds) {
    __builtin_amdgcn_global_load_lds(
        (const __attribute__((address_space(1))) unsigned int*)(uintptr_t)g,
        (__attribute__((address_space(3))) unsigned int*)(unsigned int)(uintptr_t)lds,
        16, 0, 0);
}

// ---------------------------------------------------------------------------
// Unified prep: x cast (blocks 0..8191) + three weight transposes.
__global__ __launch_bounds__(256) void prep_kernel(
    const float* __restrict__ x, u16* __restrict__ xb,
    const float* __restrict__ w_qkv, u16* __restrict__ wqkvT,
    const float* __restrict__ w_fc1, u16* __restrict__ wfc1T,
    const float* __restrict__ w_fc2, u16* __restrict__ wfc2T)
{
    const int tid = threadIdx.x;
    int blk = blockIdx.x;
    if (blk < 8192) {   // cast: whole block uniform path
        const int i = blk * 256 + tid;
        float4 v = reinterpret_cast<const float4*>(x)[i];
        ushort4v o;
        o.x = f2bfbits(v.x); o.y = f2bfbits(v.y); o.z = f2bfbits(v.z); o.w = f2bfbits(v.w);
        reinterpret_cast<ushort4v*>(xb)[i] = o;
        return;
    }
    blk -= 8192;
    const float* in; u16* out; int K, N, bx, by;
    if (blk < 3072)      { in = w_qkv; out = wqkvT; K = TC;     N = 3 * TC; bx = blk % 96;  by = blk / 96; }
    else if (blk < 7168) { blk -= 3072; in = w_fc1; out = wfc1T; K = TC;    N = 4 * TC; bx = blk & 127; by = blk >> 7; }
    else                 { blk -= 7168; in = w_fc2; out = wfc2T; K = 4 * TC; N = TC;    bx = blk & 31;  by = blk >> 5; }
    __shared__ float tile[32][33];
    const int n0 = bx * 32, k0 = by * 32;
    const int tx = tid & 31, ty = tid >> 5;   // 32 x 8
    for (int r = 0; r < 32; r += 8)
        tile[ty + r][tx] = in[(size_t)(k0 + ty + r) * N + n0 + tx];
    __syncthreads();
    for (int r = 0; r < 32; r += 8)
        out[(size_t)(n0 + ty + r) * K + k0 + tx] = f2bfbits(tile[tx][ty + r]);
}

// ---------------------------------------------------------------------------
// GEMM: 128x256 block tile, BK=64, 4 waves each 64x128 (4x8 mfma tiles).
// global_load_lds staging, XOR chunk-swizzled LDS (conflict-free b128 reads).
// m-grouped XCD swizzle: bid&7 = XCD slot; blocks sharing an A-strip are
// co-resident on one XCD (A fetched ~once). Grid must be Nb*64 blocks.
template <int GELU>
__global__ __launch_bounds__(256, 2) void gemm_bt_kernel(
    const u16* __restrict__ A, const u16* __restrict__ Bt,
    const float* __restrict__ bias, u16* __restrict__ Cmat,
    int Nb, int Ksz)
{
    __shared__ u16 As[128 * 64];
    __shared__ u16 Bs[256 * 64];
    const int tid  = threadIdx.x;
    const int wave = tid >> 6, lane = tid & 63;
    const int quad = lane >> 4, l16 = lane & 15;
    const int Nsz = Nb * 256;
    const int bid = blockIdx.x;
    const int xcd = bid & 7, qb = bid >> 3;
    const int m0 = (xcd * 8 + qb / Nb) * 128;
    const int n0 = (qb % Nb) * 256;
    const int wm = (wave >> 1) * 64, wn = (wave & 1) * 128;

    const int srow = lane >> 3;
    const int scol = ((lane & 7) ^ srow) * 8;
    const u16* ap = A  + (size_t)(m0 + wave * 32 + srow) * Ksz + scol;
    const u16* bp = Bt + (size_t)(n0 + wave * 8  + srow) * Ksz + scol;
    const size_t astep = (size_t)8  * Ksz;
    const size_t bstep = (size_t)32 * Ksz;

    floatx4 acc[4][8];
#pragma unroll
    for (int i = 0; i < 4; i++)
#pragma unroll
        for (int j = 0; j < 8; j++)
            acc[i][j] = (floatx4){0.f, 0.f, 0.f, 0.f};

    const int l7 = l16 & 7;

    for (int k0 = 0; k0 < Ksz; k0 += 64) {
        __syncthreads();
#pragma unroll
        for (int d = 0; d < 4; d++)
            gld_lds16(ap + d * astep, As + (wave * 4 + d) * 512);
#pragma unroll
        for (int d = 0; d < 8; d++)
            gld_lds16(bp + d * bstep, Bs + d * 2048 + wave * 512);
        ap += 64; bp += 64;
        __syncthreads();

#pragma unroll
        for (int t = 0; t < 2; t++) {
            const int po = ((t * 4 + quad) ^ l7) * 8;
            bf16x8 af[4], bfr[8];
#pragma unroll
            for (int i = 0; i < 4; i++)
                af[i] = *reinterpret_cast<const bf16x8*>(As + (wm + i * 16 + l16) * 64 + po);
#pragma unroll
            for (int j = 0; j < 8; j++)
                bfr[j] = *reinterpret_cast<const bf16x8*>(Bs + (wn + j * 16 + l16) * 64 + po);
#pragma unroll
            for (int i = 0; i < 4; i++)
#pragma unroll
                for (int j = 0; j < 8; j++)
                    acc[i][j] = __builtin_amdgcn_mfma_f32_16x16x32_bf16(af[i], bfr[j], acc[i][j], 0, 0, 0);
        }
    }

    // epilogue: C layout col=lane&15, row=quad*4+reg. Pair lanes (l16, l16^1):
    // even lane stores rows {0,1}, odd lane rows {2,3} of the colpair (dword stores).
    float bv[8];
#pragma unroll
    for (int j = 0; j < 8; j++) bv[j] = bias[n0 + wn + j * 16 + l16];
    const int odd = l16 & 1;
#pragma unroll
    for (int i = 0; i < 4; i++) {
        const int row0 = m0 + wm + i * 16 + quad * 4;
#pragma unroll
        for (int j = 0; j < 8; j++) {
            float v[4];
#pragma unroll
            for (int r = 0; r < 4; r++) {
                float t = acc[i][j][r] + bv[j];
                if (GELU) {
                    float u = t * (0.7978845608f + 0.0356774081f * t * t);
                    float e = EXP2F(u * (2.0f * LOG2E));
                    t = t - t * __builtin_amdgcn_rcpf(e + 1.0f);
                }
                v[r] = t;
            }
            float pv0 = __shfl_xor(v[0], 1), pv1 = __shfl_xor(v[1], 1);
            float pv2 = __shfl_xor(v[2], 1), pv3 = __shfl_xor(v[3], 1);
            float lo0 = odd ? pv2 : v[0];
            float hi0 = odd ? v[2] : pv0;
            float lo1 = odd ? pv3 : v[1];
            float hi1 = odd ? v[3] : pv1;
            unsigned int d0 = (unsigned int)f2bfbits(lo0) | ((unsigned int)f2bfbits(hi0) << 16);
            unsigned int d1 = (unsigned int)f2bfbits(lo1) | ((unsigned int)f2bfbits(hi1) << 16);
            const int row  = row0 + odd * 2;
            const int colp = n0 + wn + j * 16 + (l16 & ~1);
            *reinterpret_cast<unsigned int*>(Cmat + (size_t)row * Nsz + colp)       = d0;
            *reinterpret_cast<unsigned int*>(Cmat + (size_t)(row + 1) * Nsz + colp) = d1;
        }
    }
}

// ---------------------------------------------------------------------------
// GEMM variant: 128x128 block tile, BK=64, 4 waves each 64x64 (4x4 mfma
// tiles). Same staging/swizzle scheme as gemm_bt_kernel, but B-tile is
// staged exactly like the A-tile (32 rows/wave). Used for shapes where the
// 128x256 tile yields < 2 blocks/CU (fc2: N=1024 -> only 256 blocks).
// 32 KB LDS -> 2 blocks/CU co-resident, doubling latency-hiding.
// Grid must be Nb*64 blocks (Nb = N/128).
template <int GELU>
__global__ __launch_bounds__(256, 2) void gemm_bt128_kernel(
    const u16* __restrict__ A, const u16* __restrict__ Bt,
    const float* __restrict__ bias, u16* __restrict__ Cmat,
    int Nb, int Ksz)
{
    __shared__ u16 As[128 * 64];
    __shared__ u16 Bs[128 * 64];
    const int tid  = threadIdx.x;
    const int wave = tid >> 6, lane = tid & 63;
    const int quad = lane >> 4, l16 = lane & 15;
    const int Nsz = Nb * 128;
    const int bid = blockIdx.x;
    const int xcd = bid & 7, qb = bid >> 3;
    const int m0 = (xcd * 8 + qb / Nb) * 128;
    const int n0 = (qb % Nb) * 128;
    const int wm = (wave >> 1) * 64, wn = (wave & 1) * 64;

    const int srow = lane >> 3;
    const int scol = ((lane & 7) ^ srow) * 8;
    const u16* ap = A  + (size_t)(m0 + wave * 32 + srow) * Ksz + scol;
    const u16* bp = Bt + (size_t)(n0 + wave * 32 + srow) * Ksz + scol;
    const size_t astep = (size_t)8 * Ksz;

    floatx4 acc[4][4];
#pragma unroll
    for (int i = 0; i < 4; i++)
#pragma unroll
        for (int j = 0; j < 4; j++)
            acc[i][j] = (floatx4){0.f, 0.f, 0.f, 0.f};

    const int l7 = l16 & 7;

    for (int k0 = 0; k0 < Ksz; k0 += 64) {
        __syncthreads();
#pragma unroll
        for (int d = 0; d < 4; d++)
            gld_lds16(ap + d * astep, As + (wave * 4 + d) * 512);
#pragma unroll
        for (int d = 0; d < 4; d++)
            gld_lds16(bp + d * astep, Bs + (wave * 4 + d) * 512);
        ap += 64; bp += 64;
        __syncthreads();

#pragma unroll
        for (int t = 0; t < 2; t++) {
            const int po = ((t * 4 + quad) ^ l7) * 8;
            bf16x8 af[4], bfr[4];
#pragma unroll
            for (int i = 0; i < 4; i++)
                af[i] = *reinterpret_cast<const bf16x8*>(As + (wm + i * 16 + l16) * 64 + po);
#pragma unroll
            for (int j = 0; j < 4; j++)
                bfr[j] = *reinterpret_cast<const bf16x8*>(Bs + (wn + j * 16 + l16) * 64 + po);
#pragma unroll
            for (int i = 0; i < 4; i++)
#pragma unroll
                for (int j = 0; j < 4; j++)
                    acc[i][j] = __builtin_amdgcn_mfma_f32_16x16x32_bf16(af[i], bfr[j], acc[i][j], 0, 0, 0);
        }
    }

    // epilogue: identical scheme to gemm_bt_kernel, j-range 4.
    float bv[4];
#pragma unroll
    for (int j = 0; j < 4; j++) bv[j] = bias[n0 + wn + j * 16 + l16];
    const int odd = l16 & 1;
#pragma unroll
    for (int i = 0; i < 4; i++) {
        const int row0 = m0 + wm + i * 16 + quad * 4;
#pragma unroll
        for (int j = 0; j < 4; j++) {
            float v[4];
#pragma unroll
            for (int r = 0; r < 4; r++) {
                float t = acc[i][j][r] + bv[j];
                if (GELU) {
                    float u = t * (0.7978845608f + 0.0356774081f * t * t);
                    float e = EXP2F(u * (2.0f * LOG2E));
                    t = t - t * __builtin_amdgcn_rcpf(e + 1.0f);
                }
                v[r] = t;
            }
            float pv0 = __shfl_xor(v[0], 1), pv1 = __shfl_xor(v[1], 1);
            float pv2 = __shfl_xor(v[2], 1), pv3 = __shfl_xor(v[3], 1);
            float lo0 = odd ? pv2 : v[0];
            float hi0 = odd ? v[2] : pv0;
            float lo1 = odd ? pv3 : v[1];
            float hi1 = odd ? v[3] : pv1;
            unsigned int d0 = (unsigned int)f2bfbits(lo0) | ((unsigned int)f2bfbits(hi0) << 16);
            unsigned int d1 = (unsigned int)f2bfbits(lo1) | ((unsigned int)f2bfbits(hi1) << 16);
            const int row  = row0 + odd * 2;
            const int colp = n0 + wn + j * 16 + (l16 & ~1);
            *reinterpret_cast<unsigned int*>(Cmat + (size_t)row * Nsz + colp)       = d0;
            *reinterpret_cast<unsigned int*>(Cmat + (size_t)(row + 1) * Nsz + colp) = d1;
        }
    }
}

// ---------------------------------------------------------------------------
// Flash attention, causal, S^T form. 512 threads = 8 waves x 16 q-rows
// (128 q-rows/block), k-tile 64, double-buffered K/V LDS, 1 barrier/iter.
// Block bx processes q-tiles {bx, 15-bx} (uniform 34 iters).
__global__ __launch_bounds__(512) void attn_kernel(const u16* __restrict__ qkv,
                                                   u16* __restrict__ y)
{
    __shared__ u16 Ks[2 * 64 * 64];   // [buf][key][d], chunk-swizzled pc = c ^ (key&7)
    __shared__ u16 Vt[2 * 64 * 64];   // [buf][d][key], dword-swizzled
    __shared__ u16 Pw[8][16 * 64];    // per-wave [q][key], chunk-swizzled pc = c ^ (q&7)
    const int tid  = threadIdx.x;
    const int wave = tid >> 6, lane = tid & 63;
    const int quad = lane >> 4, l16 = lane & 15;
    const int l7   = l16 & 7;
    const int h = blockIdx.y, b = blockIdx.z;
    const int rowbase = b * TT;
    const int S3C = 3 * TC;

    // staging roles: threads 0..255 -> K tile; 256..511 -> V tile
    const int srow = (tid >> 3) & 31;
    const int c8   = (tid & 7) * 8;
    const int pcK  = ((tid & 7) ^ (srow & 7)) * 8;    // K physical chunk
    const int pvb  = (srow + ((tid & 7) << 2)) & 31;  // V physical dword base
    const bool kRole = (tid < 256);
    // compute-side
    const int pcr = (quad ^ l7) * 8;
    unsigned int* const vtw = (unsigned int*)Vt;

    for (int pass = 0; pass < 2; pass++) {
        const int qt   = pass ? (15 - (int)blockIdx.x) : (int)blockIdx.x;
        const int q0b  = qt * 128;
        const int q0w  = q0b + wave * 16;
        const int kend = q0b + 128;

        __syncthreads();   // previous pass's LDS reads complete

        // Q as B-operand frags, pre-scaled by 0.125*log2(e)
        bf16x8 qf0, qf1;
        {
            const u16* qrow = qkv + (size_t)(rowbase + q0w + l16) * S3C + h * HD + quad * 8;
            bf16x8 t0 = *reinterpret_cast<const bf16x8*>(qrow);
            bf16x8 t1 = *reinterpret_cast<const bf16x8*>(qrow + 32);
#pragma unroll
            for (int i = 0; i < 8; i++) {
                t0[i] = (bf16)((float)t0[i] * (0.125f * LOG2E));
                t1[i] = (bf16)((float)t1[i] * (0.125f * LOG2E));
            }
            qf0 = t0; qf1 = t1;
        }

        float m_s = -__builtin_inff(), l_s = 0.f;
        floatx4 o_acc[4];
#pragma unroll
        for (int n = 0; n < 4; n++) o_acc[n] = (floatx4){0.f, 0.f, 0.f, 0.f};

        // role-dependent global base (row k=0) and prefetch of tile 0
        const u16* gp = kRole
            ? qkv + (size_t)(rowbase + srow) * S3C + TC + h * HD + c8
            : qkv + (size_t)(rowbase + 2 * srow) * S3C + 2 * TC + h * HD + c8;
        const size_t g2 = kRole ? (size_t)32 * S3C : (size_t)S3C;
        ushort8 r0 = *reinterpret_cast<const ushort8*>(gp);
        ushort8 r1 = *reinterpret_cast<const ushort8*>(gp + g2);

        int buf = 0;
        for (int k0 = 0; k0 < kend; k0 += 64) {
            // write prefetched regs into LDS[buf]
            if (kRole) {
                u16* kb = Ks + buf * 4096;
                *reinterpret_cast<ushort8*>(kb + srow * 64 + pcK)        = r0;
                *reinterpret_cast<ushort8*>(kb + (srow + 32) * 64 + pcK) = r1;
            } else {
                unsigned int* vb = vtw + buf * 2048;
#pragma unroll
                for (int j = 0; j < 8; j++) {
                    unsigned int pk = (unsigned int)r0[j] | ((unsigned int)r1[j] << 16);
                    vb[(c8 + j) * 32 + (pvb ^ (j << 2))] = pk;
                }
            }
            __syncthreads();

            if (k0 + 64 < kend) {   // prefetch next tile
                const u16* gn = gp + (size_t)(k0 + 64) * S3C;
                r0 = *reinterpret_cast<const ushort8*>(gn);
                r1 = *reinterpret_cast<const ushort8*>(gn + g2);
            }

            if (k0 <= q0w + 15) {   // wave not fully masked (wave-uniform)
                const u16* ksb = Ks + buf * 4096;
                floatx4 st[4];
#pragma unroll
                for (int t = 0; t < 4; t++) {
                    const u16* krowp = ksb + (t * 16 + l16) * 64;
                    bf16x8 ka  = *reinterpret_cast<const bf16x8*>(krowp + pcr);
                    bf16x8 kb2 = *reinterpret_cast<const bf16x8*>(krowp + (pcr ^ 32));
                    floatx4 s = (floatx4){0.f, 0.f, 0.f, 0.f};
                    s = __builtin_amdgcn_mfma_f32_16x16x32_bf16(ka, qf0, s, 0, 0, 0);
                    s = __builtin_amdgcn_mfma_f32_16x16x32_bf16(kb2, qf1, s, 0, 0, 0);
                    st[t] = s;
                }
                float v[16];
                if (k0 + 63 > q0w) {   // diagonal region: causal mask (wave-uniform)
                    const int kq = k0 - q0w;
#pragma unroll
                    for (int t = 0; t < 4; t++)
#pragma unroll
                        for (int r = 0; r < 4; r++)
                            v[t * 4 + r] = (t * 16 + quad * 4 + r + kq > l16)
                                               ? -__builtin_inff() : st[t][r];
                } else {
#pragma unroll
                    for (int t = 0; t < 4; t++)
#pragma unroll
                        for (int r = 0; r < 4; r++)
                            v[t * 4 + r] = st[t][r];
                }
                float mx = v[0];
#pragma unroll
                for (int i = 1; i < 16; i++) mx = fmaxf(mx, v[i]);
                mx = fmaxf(mx, __shfl_xor(mx, 16));
                mx = fmaxf(mx, __shfl_xor(mx, 32));
                const float mnew  = fmaxf(m_s, mx);
                const float alpha = EXP2F(m_s - mnew);
                float rs = 0.f;
                u16* const pwb = Pw[wave] + l16 * 64;
#pragma unroll
                for (int t = 0; t < 4; t++) {
                    float p0 = EXP2F(v[t * 4 + 0] - mnew);
                    float p1 = EXP2F(v[t * 4 + 1] - mnew);
                    float p2 = EXP2F(v[t * 4 + 2] - mnew);
                    float p3 = EXP2F(v[t * 4 + 3] - mnew);
                    rs += (p0 + p1) + (p2 + p3);
                    ushort4v pk;
                    pk.x = f2bfbits(p0); pk.y = f2bfbits(p1);
                    pk.z = f2bfbits(p2); pk.w = f2bfbits(p3);
                    *reinterpret_cast<ushort4v*>(
                        pwb + ((2 * t + (quad >> 1)) ^ l7) * 8 + (quad & 1) * 4) = pk;
                }
                rs += __shfl_xor(rs, 16);
                rs += __shfl_xor(rs, 32);
                l_s = l_s * alpha + rs;
                m_s = mnew;
#pragma unroll
                for (int n = 0; n < 4; n++) o_acc[n] *= alpha;

                bf16x8 pf0 = *reinterpret_cast<const bf16x8*>(pwb + pcr);
                bf16x8 pf1 = *reinterpret_cast<const bf16x8*>(pwb + (pcr ^ 32));
                const unsigned int* vbb = vtw + buf * 2048;
#pragma unroll
                for (int n = 0; n < 4; n++) {
                    const int dr  = n * 16 + l16;
                    const int pd0 = ((4 * (quad + 2 * n + (l16 >> 3))) & 31) ^ (l7 << 2);
                    bf16x8 vf0 = *reinterpret_cast<const bf16x8*>(vbb + dr * 32 + pd0);
                    bf16x8 vf1 = *reinterpret_cast<const bf16x8*>(vbb + dr * 32 + (pd0 ^ 16));
                    o_acc[n] = __builtin_amdgcn_mfma_f32_16x16x32_bf16(vf0, pf0, o_acc[n], 0, 0, 0);
                    o_acc[n] = __builtin_amdgcn_mfma_f32_16x16x32_bf16(vf1, pf1, o_acc[n], 0, 0, 0);
                }
            }
            buf ^= 1;
        }

        // write O^T: col=l16=q, row=quad*4+r=d_local
        const float li = 1.0f / l_s;
        u16* yrow = y + (size_t)(rowbase + q0w + l16) * TC + h * HD;
#pragma unroll
        for (int n = 0; n < 4; n++) {
            ushort4v ov;
            ov.x = f2bfbits(o_acc[n][0] * li);
            ov.y = f2bfbits(o_acc[n][1] * li);
            ov.z = f2bfbits(o_acc[n][2] * li);
            ov.w = f2bfbits(o_acc[n][3] * li);
            *reinterpret_cast<ushort4v*>(yrow + n * 16 + quad * 4) = ov;
        }
    }
}

// ---------------------------------------------------------------------------
template <typename AT, typename OT>
__global__ __launch_bounds__(256) void ln_kernel(
    const AT* __restrict__ a, const bf16* __restrict__ bres,
    const float* __restrict__ g, const float* __restrict__ be,
    OT* __restrict__ out)
{
    const int row = blockIdx.x;
    const int tid = threadIdx.x;
    const size_t base = (size_t)row * TC;
    float v[4];
    for (int i = 0; i < 4; i++) {
        const int c = tid + i * 256;
        v[i] = (float)a[base + c] + (float)bres[base + c];
    }
    float s  = v[0] + v[1] + v[2] + v[3];
    float sq = v[0]*v[0] + v[1]*v[1] + v[2]*v[2] + v[3]*v[3];
    for (int off = 32; off >= 1; off >>= 1) {
        s  += __shfl_xor(s, off, 64);
        sq += __shfl_xor(sq, off, 64);
    }
    __shared__ float red[8];
    const int wv = tid >> 6, lane = tid & 63;
    if (lane == 0) { red[wv] = s; red[4 + wv] = sq; }
    __syncthreads();
    s  = red[0] + red[1] + red[2] + red[3];
    sq = red[4] + red[5] + red[6] + red[7];
    const float mu   = s * (1.0f / TC);
    const float var  = sq * (1.0f / TC) - mu * mu;
    const float rsig = rsqrtf(var + 1e-5f);
    for (int i = 0; i < 4; i++) {
        const int c = tid + i * 256;
        out[base + c] = (OT)((v[i] - mu) * rsig * g[c] + be[c]);
    }
}

// ---------------------------------------------------------------------------
extern "C" void kernel_launch(void* const* d_in, const int* in_sizes, int n_in,
                              void* d_out, int out_size, void* d_ws, size_t ws_size,
                              hipStream_t stream)
{
    const float* x     = (const float*)d_in[0];
    const float* w_qkv = (const float*)d_in[1];
    const float* b_qkv = (const float*)d_in[2];
    const float* ln1_g = (const float*)d_in[3];
    const float* ln1_b = (const float*)d_in[4];
    const float* w_fc1 = (const float*)d_in[5];
    const float* b_fc1 = (const float*)d_in[6];
    const float* w_fc2 = (const float*)d_in[7];
    const float* b_fc2 = (const float*)d_in[8];
    const float* ln2_g = (const float*)d_in[9];
    const float* ln2_b = (const float*)d_in[10];
    float* out = (float*)d_out;

    char* ws = (char*)d_ws;
    const size_t MB = 1ull << 20;
    u16* xb    = (u16*)(ws + 0);        // [8192][1024]  16 MB
    u16* wqkvT = (u16*)(ws + 16 * MB);  // [3072][1024]   6 MB
    u16* wfc1T = (u16*)(ws + 22 * MB);  // [4096][1024]   8 MB
    u16* wfc2T = (u16*)(ws + 30 * MB);  // [1024][4096]   8 MB
    u16* qkv   = (u16*)(ws + 38 * MB);  // [8192][3072]  48 MB
    u16* yb    = (u16*)(ws + 86 * MB);  // [8192][1024]  16 MB
    u16* x1    = (u16*)(ws + 102 * MB); // [8192][1024]  16 MB
    u16* hb    = (u16*)(ws + 118 * MB); // [8192][4096]  64 MB
    u16* mlp   = (u16*)(ws + 38 * MB);  // reuse qkv region

    prep_kernel<<<19456, 256, 0, stream>>>(x, xb, w_qkv, wqkvT, w_fc1, wfc1T, w_fc2, wfc2T);

    gemm_bt_kernel<0><<<12 * 64, 256, 0, stream>>>(xb, wqkvT, b_qkv, qkv, 12, TC);
    attn_kernel<<<dim3(8, NH, TB), 512, 0, stream>>>(qkv, yb);
    ln_kernel<float, bf16><<<MROWS, 256, 0, stream>>>(x, (const bf16*)yb, ln1_g, ln1_b, (bf16*)x1);
    gemm_bt_kernel<1><<<16 * 64, 256, 0, stream>>>((const u16*)x1, wfc1T, b_fc1, hb, 16, TC);
    gemm_bt128_kernel<0><<<8 * 64, 256, 0, stream>>>(hb, wfc2T, b_fc2, mlp, 8, 4 * TC);
    ln_kernel<bf16, float><<<MROWS, 256, 0, stream>>>(
        (const bf16*)x1, (const bf16*)mlp, ln2_g, ln2_b, out);
}